// Round 16
// baseline (121.085 us; speedup 1.0000x reference)
//
#include <hip/hip_runtime.h>
#include <hip/hip_bf16.h>

#define SEQ    4096
#define CDIM   512
#define NHEADS 8
#define HDIM   64
// fold softmax scale and log2(e) into Q once: exp(s*SCALE) == exp2(s')
#define QSCALE 0.18033688f   // 0.125 * 1.4426950408889634

typedef __attribute__((ext_vector_type(4))) float f32x4;
typedef __attribute__((ext_vector_type(8))) short bf16x8;

// LDS swizzle for tiles with 64-bf16 (128B) row stride
__device__ __forceinline__ int swz(int row, int col) {
    int b = (row << 7) + (col << 1);
    b ^= (row & 7) << 4;
    return b >> 1;
}

// LDS swizzle for tiles with 32-bf16 (64B) row stride; c = 8-elem col block (0..3)
__device__ __forceinline__ int swz64(int row, int c) {
    return ((row << 6) + (((c) ^ ((row >> 1) & 3)) << 4)) >> 1;
}

__device__ __forceinline__ short f2bf(float f) {
    union { __hip_bfloat16 h; short s; } u;
    u.h = __float2bfloat16(f);
    return u.s;
}

// async global->LDS, 16B per lane; LDS dest = wave-uniform base + lane*16
__device__ __forceinline__ void gl16(const void* g, void* l) {
    __builtin_amdgcn_global_load_lds(
        (const __attribute__((address_space(1))) unsigned int*)g,
        (__attribute__((address_space(3))) unsigned int*)l,
        16, 0, 0);
}

// ---------------- f32 -> bf16 pre-pass for all three arrays (one launch)
__global__ __launch_bounds__(256) void cvt3_k(
    const float* __restrict__ a0, short* __restrict__ o0, int c0,
    const float* __restrict__ a1, short* __restrict__ o1, int c1,
    const float* __restrict__ a2, short* __restrict__ o2, int c2)
{
    const int total = c0 + c1 + c2;
    int i = blockIdx.x * 256 + threadIdx.x;
    const int stride = gridDim.x * 256;
    for (; i < total; i += stride) {
        const float* a; short* o; int j;
        if (i < c0)           { a = a0; o = o0; j = i; }
        else if (i < c0 + c1) { a = a1; o = o1; j = i - c0; }
        else                  { a = a2; o = o2; j = i - c0 - c1; }
        float4 v = ((const float4*)a)[j];
        short4 r;
        r.x = f2bf(v.x); r.y = f2bf(v.y); r.z = f2bf(v.z); r.w = f2bf(v.w);
        ((short4*)o)[j] = r;
    }
}

// =============== shared GEMM core (counted-vmcnt pipeline, K=512, 16 tiles of 32)
// 256 threads, tile 128x128, A[4]/B[4] 8KB buffers (64KB LDS), vmcnt(8) steady.

#define GEMM_PRELUDE(APTR, BPTR)                                               \
    __shared__ alignas(16) short As[4][128 * 32];                              \
    __shared__ alignas(16) short Bs[4][128 * 32];                              \
    const int tid  = threadIdx.x;                                              \
    const int lane = tid & 63;                                                 \
    const int l15  = lane & 15;                                                \
    const int lg   = lane >> 4;                                                \
    const int wv   = tid >> 6;                                                 \
    const int wy   = wv >> 1, wx = wv & 1;                                     \
    const int m0 = blockIdx.x * 128;                                           \
    const int n0 = blockIdx.y * 128;                                           \
    const f32x4 fzero = {0.f, 0.f, 0.f, 0.f};                                  \
    f32x4 acc[4][4];                                                           \
    _Pragma("unroll")                                                          \
    for (int i = 0; i < 4; ++i)                                                \
        _Pragma("unroll")                                                      \
        for (int j = 0; j < 4; ++j)                                            \
            acc[i][j] = fzero;                                                 \
    /* staging: slot t = wv*128 + i*64 + lane; row = wv*32+i*16+(lane>>2),     \
       c = (lane&3)^((lane>>3)&3); src byte = row*1024 + c*16 (+t_tile*64) */  \
    const int srow = wv * 32 + (lane >> 2);                                    \
    const int scb  = ((lane & 3) ^ ((lane >> 3) & 3)) << 4;                    \
    const char* agp = (const char*)(APTR) + (size_t)(m0 + srow) * 1024 + scb;  \
    const char* bgp = (const char*)(BPTR) + (size_t)(n0 + srow) * 1024 + scb;  \
    const int ldst = wv * 2048;

#define GSTAGE(T_, BUF_) do {                                                  \
    _Pragma("unroll")                                                          \
    for (int i_ = 0; i_ < 2; ++i_) {                                           \
        gl16(agp + (T_) * 64 + i_ * 16384, (char*)&As[BUF_][0] + ldst + i_ * 1024); \
        gl16(bgp + (T_) * 64 + i_ * 16384, (char*)&Bs[BUF_][0] + ldst + i_ * 1024); \
    } } while (0)

#define GCOMP(BUF_) do {                                                       \
    bf16x8 afr[4], bfr[4];                                                     \
    _Pragma("unroll")                                                          \
    for (int i = 0; i < 4; ++i) {                                              \
        afr[i] = *(const bf16x8*)(&As[BUF_][swz64(wy * 64 + i * 16 + l15, lg)]); \
        bfr[i] = *(const bf16x8*)(&Bs[BUF_][swz64(wx * 64 + i * 16 + l15, lg)]); \
    }                                                                          \
    __builtin_amdgcn_s_setprio(1);                                             \
    _Pragma("unroll")                                                          \
    for (int i = 0; i < 4; ++i)                                                \
        _Pragma("unroll")                                                      \
        for (int j = 0; j < 4; ++j)                                            \
            acc[i][j] = __builtin_amdgcn_mfma_f32_16x16x32_bf16(afr[i], bfr[j], acc[i][j], 0, 0, 0); \
    __builtin_amdgcn_s_setprio(0);                                             \
} while (0)

#define GWAITBAR(N_) do {                                                      \
    asm volatile("s_waitcnt vmcnt(" #N_ ")" ::: "memory");                     \
    __builtin_amdgcn_s_barrier();                                              \
    asm volatile("" ::: "memory");                                             \
} while (0)

#define GEMM_MAIN                                                              \
    GSTAGE(0, 0); GSTAGE(1, 1); GSTAGE(2, 2);                                  \
    _Pragma("unroll")                                                          \
    for (int it = 0; it < 3; ++it) {                                           \
        const int t = it * 4;                                                  \
        GWAITBAR(8); GSTAGE(t + 3, 3); GCOMP(0);                               \
        GWAITBAR(8); GSTAGE(t + 4, 0); GCOMP(1);                               \
        GWAITBAR(8); GSTAGE(t + 5, 1); GCOMP(2);                               \
        GWAITBAR(8); GSTAGE(t + 6, 2); GCOMP(3);                               \
    }                                                                          \
    GWAITBAR(8); GSTAGE(15, 3); GCOMP(0);                                      \
    GWAITBAR(8); GCOMP(1);                                                     \
    GWAITBAR(4); GCOMP(2);                                                     \
    GWAITBAR(0); GCOMP(3);

// ---------------- QKV GEMM: xb[8192,512]bf16 @ wb[1536,512]^T
__global__ __launch_bounds__(256) void qkv_gemm_k(
    const short* __restrict__ xb, const short* __restrict__ wb,
    short* __restrict__ qb, short* __restrict__ kb, short* __restrict__ vtb)
{
    GEMM_PRELUDE(xb, wb)
    GEMM_MAIN

    // epilogue: Q (scaled), K as [bh][n][64]; V^T blocked per 32 kv with col-perm
    #pragma unroll
    for (int j = 0; j < 4; ++j) {
        const int d = n0 + wx * 64 + j * 16 + l15;
        const int s = d >> 9;
        const int h = (d >> 6) & 7;
        const int e = d & 63;
        #pragma unroll
        for (int i = 0; i < 4; ++i) {
            #pragma unroll
            for (int r = 0; r < 4; ++r) {
                const int m  = m0 + wy * 64 + i * 16 + lg * 4 + r;
                const int bb = m >> 12;
                const int n  = m & (SEQ - 1);
                const int bh = bb * NHEADS + h;
                const float v = acc[i][j][r];
                if (s == 0) {
                    qb[(((size_t)bh * SEQ + n) << 6) + e] = f2bf(v * QSCALE);
                } else if (s == 1) {
                    kb[(((size_t)bh * SEQ + n) << 6) + e] = f2bf(v);
                } else {
                    const int c  = n & 31;
                    const int cp = (c & 3) | ((c & 0x0C) << 1) | ((c & 0x10) >> 2);
                    vtb[((size_t)bh << 18) + ((size_t)(n >> 5) << 11) + (e << 5) + cp] = f2bf(v);
                }
            }
        }
    }
}

// ---------------- proj GEMM + bias + residual: y = x + ao@w^T + bp
__global__ __launch_bounds__(256) void proj_k(
    const short* __restrict__ ao, const short* __restrict__ wpb,
    const float* __restrict__ bp, const float* __restrict__ x,
    float* __restrict__ y)
{
    GEMM_PRELUDE(ao, wpb)
    GEMM_MAIN

    #pragma unroll
    for (int i = 0; i < 4; ++i) {
        #pragma unroll
        for (int j = 0; j < 4; ++j) {
            const int d = n0 + wx * 64 + j * 16 + l15;
            #pragma unroll
            for (int r = 0; r < 4; ++r) {
                const int m = m0 + wy * 64 + i * 16 + lg * 4 + r;
                const size_t idx = (size_t)m * CDIM + d;
                y[idx] = acc[i][j][r] + bp[d] + x[idx];
            }
        }
    }
}

// ---------------- Flash attention: counted-vmcnt pipeline (T3+T4) + T5 setprio.
//   Split-KV (2 groups x 4 waves), 32-kv tiles, K[4]/V[4] group-shared buffers,
//   per tile: s_waitcnt vmcnt(4) -> raw s_barrier -> stage(t+3) -> compute(t).
//   Tail steps use vmcnt(4/2/0) so the last tiles' loads are guaranteed landed.
__global__ __launch_bounds__(512) void attn_k(
    const short* __restrict__ qb, const short* __restrict__ kb, const short* __restrict__ vtb,
    short* __restrict__ ob)
{
    __shared__ alignas(16) char smem[65536];   // 2 groups x (K[4]+V[4]) x 4KB
    const int tid  = threadIdx.x;
    const int lane = tid & 63;
    const int l15  = lane & 15;
    const int lg   = lane >> 4;
    const int wv   = (tid >> 6) & 3;    // wave within group
    const int wg   = tid >> 8;          // wave group = kv half
    const int lin  = blockIdx.x;
    const int bh   = lin & 15;          // same-bh blocks land on one XCD (L2 locality)
    const int q0   = (lin >> 4) << 7;   // 128 q-rows per block
    const int b    = bh >> 3, h = bh & 7;
    const size_t base = (size_t)bh * SEQ * HDIM;

    // Q fragments: wave owns 32 q-rows (2 fragments of 16)
    bf16x8 qf[2][2];
    #pragma unroll
    for (int qi = 0; qi < 2; ++qi) {
        const short* qp = qb + base + (size_t)(q0 + wv * 32 + qi * 16 + l15) * HDIM + lg * 8;
        qf[qi][0] = *(const bf16x8*)(qp);
        qf[qi][1] = *(const bf16x8*)(qp + 32);
    }

    const f32x4 fzero = {0.f, 0.f, 0.f, 0.f};
    f32x4 acc[2][4];    // partial O for this kv half
    f32x4 lacc[2];      // partial row sums via ones-MFMA
    #pragma unroll
    for (int qi = 0; qi < 2; ++qi) {
        lacc[qi] = fzero;
        #pragma unroll
        for (int di = 0; di < 4; ++di) acc[qi][di] = fzero;
    }

    bf16x8 ones;
    #pragma unroll
    for (int e = 0; e < 8; ++e) ones[e] = (short)0x3F80;  // bf16 1.0

    const int t0  = wv * 64 + lane;
    const int cbs = ((t0 & 7) ^ ((t0 >> 3) & 7)) << 4;
    const int ghb = wg * 262144;   // kv-half byte offset (2048 kv * 128B)
    const char* kgp = (const char*)(kb + base) + ghb + (((t0 >> 3) << 7) + cbs);
    const char* vgp = (const char*)(vtb + ((size_t)bh << 18)) + ghb + (((t0 >> 3) << 7) + cbs);
    char* const gb = smem + wg * 32768;
    const short* Kb0 = (const short*)(gb);
    const short* Kb1 = (const short*)(gb + 4096);
    const short* Kb2 = (const short*)(gb + 8192);
    const short* Kb3 = (const short*)(gb + 12288);
    const short* Vb0 = (const short*)(gb + 16384);
    const short* Vb1 = (const short*)(gb + 20480);
    const short* Vb2 = (const short*)(gb + 24576);
    const short* Vb3 = (const short*)(gb + 28672);
    char* Ks0 = gb +     0 + wv * 1024;
    char* Ks1 = gb +  4096 + wv * 1024;
    char* Ks2 = gb +  8192 + wv * 1024;
    char* Ks3 = gb + 12288 + wv * 1024;
    char* Vs0 = gb + 16384 + wv * 1024;
    char* Vs1 = gb + 20480 + wv * 1024;
    char* Vs2 = gb + 24576 + wv * 1024;
    char* Vs3 = gb + 28672 + wv * 1024;

    #define MFMA16(a_, b_, c_) __builtin_amdgcn_mfma_f32_16x16x32_bf16(a_, b_, c_, 0, 0, 0)

    #define STAGE2(T_, KS, VS) do {                    \
        gl16(kgp + (T_) * 4096, (KS));                 \
        gl16(vgp + (T_) * 4096, (VS));                 \
    } while (0)

    #define COMPUTE(KR, VR) do {                                               \
        f32x4 s00 = fzero, s01 = fzero, s10 = fzero, s11 = fzero;              \
        __builtin_amdgcn_s_setprio(1);                                         \
        {                                                                      \
            bf16x8 kf_;                                                        \
            kf_ = *(const bf16x8*)(&(KR)[swz(l15, lg * 8)]);                   \
            s00 = MFMA16(kf_, qf[0][0], s00);                                  \
            s10 = MFMA16(kf_, qf[1][0], s10);                                  \
            kf_ = *(const bf16x8*)(&(KR)[swz(l15, 32 + lg * 8)]);              \
            s00 = MFMA16(kf_, qf[0][1], s00);                                  \
            s10 = MFMA16(kf_, qf[1][1], s10);                                  \
            kf_ = *(const bf16x8*)(&(KR)[swz(16 + l15, lg * 8)]);              \
            s01 = MFMA16(kf_, qf[0][0], s01);                                  \
            s11 = MFMA16(kf_, qf[1][0], s11);                                  \
            kf_ = *(const bf16x8*)(&(KR)[swz(16 + l15, 32 + lg * 8)]);         \
            s01 = MFMA16(kf_, qf[0][1], s01);                                  \
            s11 = MFMA16(kf_, qf[1][1], s11);                                  \
        }                                                                      \
        __builtin_amdgcn_s_setprio(0);                                         \
        bf16x8 pa0, pa1;                                                       \
        _Pragma("unroll")                                                      \
        for (int r_ = 0; r_ < 4; ++r_) {                                       \
            pa0[r_]     = f2bf(__builtin_amdgcn_exp2f(s00[r_]));               \
            pa0[4 + r_] = f2bf(__builtin_amdgcn_exp2f(s01[r_]));               \
            pa1[r_]     = f2bf(__builtin_amdgcn_exp2f(s10[r_]));               \
            pa1[4 + r_] = f2bf(__builtin_amdgcn_exp2f(s11[r_]));               \
        }                                                                      \
        __builtin_amdgcn_s_setprio(1);                                         \
        lacc[0] = MFMA16(pa0, ones, lacc[0]);                                  \
        lacc[1] = MFMA16(pa1, ones, lacc[1]);                                  \
        _Pragma("unroll")                                                      \
        for (int di_ = 0; di_ < 4; ++di_) {                                    \
            bf16x8 vf_ = *(const bf16x8*)(&(VR)[swz(di_ * 8 + (l15 >> 1),      \
                                                    (l15 & 1) * 32 + lg * 8)]);\
            acc[0][di_] = MFMA16(pa0, vf_, acc[0][di_]);                       \
            acc[1][di_] = MFMA16(pa1, vf_, acc[1][di_]);                       \
        }                                                                      \
        __builtin_amdgcn_s_setprio(0);                                         \
    } while (0)

    #define AWAITBAR(N_) do {                                      \
        asm volatile("s_waitcnt vmcnt(" #N_ ")" ::: "memory");     \
        __builtin_amdgcn_s_barrier();                              \
        asm volatile("" ::: "memory");                             \
    } while (0)

    // prologue: stage tiles 0,1,2 (6 loads in flight)
    STAGE2(0, Ks0, Vs0);
    STAGE2(1, Ks1, Vs1);
    STAGE2(2, Ks2, Vs2);

    // steady: tiles 0..60 stage t+3; tail 61/62/63 with decreasing waits
    for (int it = 0; it < 15; ++it) {
        const int t = it << 2;
        AWAITBAR(4); STAGE2(t + 3, Ks3, Vs3); COMPUTE(Kb0, Vb0);
        AWAITBAR(4); STAGE2(t + 4, Ks0, Vs0); COMPUTE(Kb1, Vb1);
        AWAITBAR(4); STAGE2(t + 5, Ks1, Vs1); COMPUTE(Kb2, Vb2);
        AWAITBAR(4); STAGE2(t + 6, Ks2, Vs2); COMPUTE(Kb3, Vb3);
    }
    AWAITBAR(4); STAGE2(63, Ks3, Vs3); COMPUTE(Kb0, Vb0);   // t=60
    AWAITBAR(4); COMPUTE(Kb1, Vb1);                          // t=61
    AWAITBAR(2); COMPUTE(Kb2, Vb2);                          // t=62
    AWAITBAR(0); COMPUTE(Kb3, Vb3);                          // t=63
    #undef AWAITBAR
    #undef COMPUTE
    #undef STAGE2
    #undef MFMA16

    // ---- combine the two kv-halves: O = (O0+O1)/(l0+l1) ----
    __syncthreads();   // all K/V reads done; smem reusable as f32 exchange buffer
    float* xch = (float*)smem;
    const int xi = (wv * 64 + lane) * 44;   // 44 f32 stride: 16B-aligned, bank-spread
    if (wg == 1) {
        #pragma unroll
        for (int qi = 0; qi < 2; ++qi) {
            #pragma unroll
            for (int di = 0; di < 4; ++di)
                *(f32x4*)(xch + xi + qi * 16 + di * 4) = acc[qi][di];
            *(f32x4*)(xch + xi + 32 + qi * 4) = lacc[qi];
        }
    }
    __syncthreads();
    if (wg == 0) {
        #pragma unroll
        for (int qi = 0; qi < 2; ++qi) {
            #pragma unroll
            for (int di = 0; di < 4; ++di)
                acc[qi][di] += *(const f32x4*)(xch + xi + qi * 16 + di * 4);
            lacc[qi] += *(const f32x4*)(xch + xi + 32 + qi * 4);
        }
        #pragma unroll
        for (int qi = 0; qi < 2; ++qi) {
            float inv[4];
            #pragma unroll
            for (int r = 0; r < 4; ++r) inv[r] = 1.0f / lacc[qi][r];
            #pragma unroll
            for (int di = 0; di < 4; ++di) {
                const int e = di * 16 + l15;
                #pragma unroll
                for (int r = 0; r < 4; ++r) {
                    const int qn = q0 + wv * 32 + qi * 16 + lg * 4 + r;
                    ob[((size_t)(b * SEQ + qn) << 9) + h * 64 + e] = f2bf(acc[qi][di][r] * inv[r]);
                }
            }
        }
    }
}

// ---------------- LayerNorm in place over d_out rows (512 f32 each), 1 wave/row
__global__ __launch_bounds__(256) void ln_k(
    float* __restrict__ y, const float* __restrict__ gm, const float* __restrict__ bt)
{
    const int lane = threadIdx.x & 63;
    const int row  = blockIdx.x * 4 + (threadIdx.x >> 6);
    float* p = y + (size_t)row * CDIM;
    float4 a = *(const float4*)(p + lane * 4);
    float4 b = *(const float4*)(p + 256 + lane * 4);
    float s = a.x + a.y + a.z + a.w + b.x + b.y + b.z + b.w;
    float q = a.x * a.x + a.y * a.y + a.z * a.z + a.w * a.w
            + b.x * b.x + b.y * b.y + b.z * b.z + b.w * b.w;
    #pragma unroll
    for (int mm = 1; mm < 64; mm <<= 1) {
        s += __shfl_xor(s, mm, 64);
        q += __shfl_xor(q, mm, 64);
    }
    const float mean = s * (1.0f / CDIM);
    const float var  = q * (1.0f / CDIM) - mean * mean;
    const float inv  = rsqrtf(var + 1e-5f);
    float4 g0 = *(const float4*)(gm + lane * 4);
    float4 g1 = *(const float4*)(gm + 256 + lane * 4);
    float4 t0 = *(const float4*)(bt + lane * 4);
    float4 t1 = *(const float4*)(bt + 256 + lane * 4);
    float4 r0, r1;
    r0.x = (a.x - mean) * inv * g0.x + t0.x;
    r0.y = (a.y - mean) * inv * g0.y + t0.y;
    r0.z = (a.z - mean) * inv * g0.z + t0.z;
    r0.w = (a.w - mean) * inv * g0.w + t0.w;
    r1.x = (b.x - mean) * inv * g1.x + t1.x;
    r1.y = (b.y - mean) * inv * g1.y + t1.y;
    r1.z = (b.z - mean) * inv * g1.z + t1.z;
    r1.w = (b.w - mean) * inv * g1.w + t1.w;
    *(float4*)(p + lane * 4) = r0;
    *(float4*)(p + 256 + lane * 4) = r1;
}

extern "C" void kernel_launch(void* const* d_in, const int* in_sizes, int n_in,
                              void* d_out, int out_size, void* d_ws, size_t ws_size,
                              hipStream_t stream)
{
    const float* x      = (const float*)d_in[0];
    const float* w_qkv  = (const float*)d_in[1];
    const float* w_proj = (const float*)d_in[2];
    const float* b_proj = (const float*)d_in[3];
    const float* gamma  = (const float*)d_in[4];
    const float* beta   = (const float*)d_in[5];
    float* out = (float*)d_out;

    const size_t qkv_elems = (size_t)16 * SEQ * HDIM;
    short* qb    = (short*)d_ws;
    short* kb    = qb + qkv_elems;
    short* vtb   = kb + qkv_elems;
    short* ob    = vtb + qkv_elems;
    short* xb    = ob;                     // alias: xb dead before attn writes ob
    short* wqkvb = ob + qkv_elems;
    short* wpb   = wqkvb + (size_t)3 * CDIM * CDIM;

    cvt3_k    <<<dim3(1024),   256, 0, stream>>>(
        x, xb, (2 * SEQ * CDIM) / 4,
        w_qkv, wqkvb, (3 * CDIM * CDIM) / 4,
        w_proj, wpb, (CDIM * CDIM) / 4);
    qkv_gemm_k<<<dim3(64, 12), 256, 0, stream>>>(xb, wqkvb, qb, kb, vtb);
    attn_k    <<<dim3(512),    512, 0, stream>>>(qb, kb, vtb, ob);
    proj_k    <<<dim3(64, 4),  256, 0, stream>>>(ob, wpb, b_proj, x, out);
    ln_k      <<<dim3(2048),   256, 0, stream>>>(out, gamma, beta);
}

// Round 17
// 111.872 us; speedup vs baseline: 1.0824x; 1.0824x over previous
//
#include <hip/hip_runtime.h>
#include <hip/hip_bf16.h>

#define SEQ    4096
#define CDIM   512
#define NHEADS 8
#define HDIM   64
// fold softmax scale and log2(e) into Q once: exp(s*SCALE) == exp2(s')
#define QSCALE 0.18033688f   // 0.125 * 1.4426950408889634

typedef __attribute__((ext_vector_type(4))) float f32x4;
typedef __attribute__((ext_vector_type(8))) short bf16x8;

// LDS swizzle for tiles with 64-bf16 (128B) row stride: spread rows across banks.
__device__ __forceinline__ int swz(int row, int col) {
    int b = (row << 7) + (col << 1);
    b ^= (row & 7) << 4;
    return b >> 1;
}

__device__ __forceinline__ short f2bf(float f) {
    union { __hip_bfloat16 h; short s; } u;
    u.h = __float2bfloat16(f);
    return u.s;
}

// async global->LDS, 16B per lane; LDS dest = wave-uniform base + lane*16
__device__ __forceinline__ void gl16(const void* g, void* l) {
    __builtin_amdgcn_global_load_lds(
        (const __attribute__((address_space(1))) unsigned int*)g,
        (__attribute__((address_space(3))) unsigned int*)l,
        16, 0, 0);
}

// ---------------- f32 -> bf16 pre-pass for all three arrays (one launch)
__global__ __launch_bounds__(256) void cvt3_k(
    const float* __restrict__ a0, short* __restrict__ o0, int c0,
    const float* __restrict__ a1, short* __restrict__ o1, int c1,
    const float* __restrict__ a2, short* __restrict__ o2, int c2)
{
    const int total = c0 + c1 + c2;
    int i = blockIdx.x * 256 + threadIdx.x;
    const int stride = gridDim.x * 256;
    for (; i < total; i += stride) {
        const float* a; short* o; int j;
        if (i < c0)           { a = a0; o = o0; j = i; }
        else if (i < c0 + c1) { a = a1; o = o1; j = i - c0; }
        else                  { a = a2; o = o2; j = i - c0 - c1; }
        float4 v = ((const float4*)a)[j];
        short4 r;
        r.x = f2bf(v.x); r.y = f2bf(v.y); r.z = f2bf(v.z); r.w = f2bf(v.w);
        ((short4*)o)[j] = r;
    }
}

// ---------------- QKV GEMM (bf16 inputs): xb[8192,512] @ wb[1536,512]^T
__global__ __launch_bounds__(256) void qkv_gemm_k(
    const short* __restrict__ xb, const short* __restrict__ wb,
    short* __restrict__ qb, short* __restrict__ kb, short* __restrict__ vtb)
{
    __shared__ alignas(16) short As[2][128 * 64];
    __shared__ alignas(16) short Bs[2][128 * 64];
    const int tid  = threadIdx.x;
    const int lane = tid & 63;
    const int l15  = lane & 15;
    const int lg   = lane >> 4;
    const int wv   = tid >> 6;
    const int wy   = wv >> 1, wx = wv & 1;
    const int m0 = blockIdx.x * 128;
    const int n0 = blockIdx.y * 128;

    const f32x4 fzero = {0.f, 0.f, 0.f, 0.f};
    f32x4 acc[4][4];
    #pragma unroll
    for (int i = 0; i < 4; ++i)
        #pragma unroll
        for (int j = 0; j < 4; ++j)
            acc[i][j] = fzero;

    const int row0 = wv * 8 + (lane >> 3);
    const int cb   = ((lane & 7) ^ (lane >> 3)) << 4;
    const char* agp = (const char*)xb + (size_t)(m0 + row0) * 1024 + cb;
    const char* bgp = (const char*)wb + (size_t)(n0 + row0) * 1024 + cb;
    char* al0 = (char*)&As[0][0] + wv * 1024;
    char* al1 = (char*)&As[1][0] + wv * 1024;
    char* bl0 = (char*)&Bs[0][0] + wv * 1024;
    char* bl1 = (char*)&Bs[1][0] + wv * 1024;

    #define QSTAGE(al, bl, kofs) do {                                  \
        _Pragma("unroll")                                              \
        for (int i_ = 0; i_ < 4; ++i_) {                               \
            gl16(agp + (kofs) + i_ * 32768, (al) + i_ * 4096);         \
            gl16(bgp + (kofs) + i_ * 32768, (bl) + i_ * 4096);         \
        } } while (0)

    QSTAGE(al0, bl0, 0);

    int cur = 0;
    for (int k0 = 0; k0 < CDIM; k0 += 64) {
        asm volatile("s_waitcnt vmcnt(0)" ::: "memory");
        __syncthreads();
        if (k0 + 64 < CDIM) {
            if (cur == 0) QSTAGE(al1, bl1, (k0 + 64) * 2);
            else          QSTAGE(al0, bl0, (k0 + 64) * 2);
        }
        const short* Ac = cur ? &As[1][0] : &As[0][0];
        const short* Bc = cur ? &Bs[1][0] : &Bs[0][0];

        #pragma unroll
        for (int ks = 0; ks < 2; ++ks) {
            bf16x8 afr[4], bfr[4];
            #pragma unroll
            for (int i = 0; i < 4; ++i) {
                afr[i] = *(const bf16x8*)(&Ac[swz(wy * 64 + i * 16 + l15, ks * 32 + lg * 8)]);
                bfr[i] = *(const bf16x8*)(&Bc[swz(wx * 64 + i * 16 + l15, ks * 32 + lg * 8)]);
            }
            #pragma unroll
            for (int i = 0; i < 4; ++i)
                #pragma unroll
                for (int j = 0; j < 4; ++j)
                    acc[i][j] = __builtin_amdgcn_mfma_f32_16x16x32_bf16(afr[i], bfr[j], acc[i][j], 0, 0, 0);
        }
        cur ^= 1;
    }
    #undef QSTAGE

    // epilogue: Q (scaled), K as [bh][n][64]; V^T blocked per 32 kv with col-perm
    #pragma unroll
    for (int j = 0; j < 4; ++j) {
        const int d = n0 + wx * 64 + j * 16 + l15;
        const int s = d >> 9;
        const int h = (d >> 6) & 7;
        const int e = d & 63;
        #pragma unroll
        for (int i = 0; i < 4; ++i) {
            #pragma unroll
            for (int r = 0; r < 4; ++r) {
                const int m  = m0 + wy * 64 + i * 16 + lg * 4 + r;
                const int bb = m >> 12;
                const int n  = m & (SEQ - 1);
                const int bh = bb * NHEADS + h;
                const float v = acc[i][j][r];
                if (s == 0) {
                    qb[(((size_t)bh * SEQ + n) << 6) + e] = f2bf(v * QSCALE);
                } else if (s == 1) {
                    kb[(((size_t)bh * SEQ + n) << 6) + e] = f2bf(v);
                } else {
                    // V blocked [bh][n>>5][d=e][cp]: within-32 kv perm
                    const int c  = n & 31;
                    const int cp = (c & 3) | ((c & 0x0C) << 1) | ((c & 0x10) >> 2);
                    vtb[((size_t)bh << 18) + ((size_t)(n >> 5) << 11) + (e << 5) + cp] = f2bf(v);
                }
            }
        }
    }
}

// ---------------- Flash attention: counted-vmcnt pipeline (T3+T4) + T5 setprio.
//   Split-KV (2 groups x 4 waves), 32-kv tiles, K[4]/V[4] group-shared buffers,
//   per tile: s_waitcnt vmcnt(4) -> raw s_barrier -> stage(t+3) -> compute(t).
//   Tail steps use vmcnt(4/2/0) so the last tiles' loads are guaranteed landed.
__global__ __launch_bounds__(512) void attn_k(
    const short* __restrict__ qb, const short* __restrict__ kb, const short* __restrict__ vtb,
    short* __restrict__ ob)
{
    __shared__ alignas(16) char smem[65536];   // 2 groups x (K[4]+V[4]) x 4KB
    const int tid  = threadIdx.x;
    const int lane = tid & 63;
    const int l15  = lane & 15;
    const int lg   = lane >> 4;
    const int wv   = (tid >> 6) & 3;    // wave within group
    const int wg   = tid >> 8;          // wave group = kv half
    const int lin  = blockIdx.x;
    const int bh   = lin & 15;          // same-bh blocks land on one XCD (L2 locality)
    const int q0   = (lin >> 4) << 7;   // 128 q-rows per block
    const int b    = bh >> 3, h = bh & 7;
    const size_t base = (size_t)bh * SEQ * HDIM;

    // Q fragments: wave owns 32 q-rows (2 fragments of 16)
    bf16x8 qf[2][2];
    #pragma unroll
    for (int qi = 0; qi < 2; ++qi) {
        const short* qp = qb + base + (size_t)(q0 + wv * 32 + qi * 16 + l15) * HDIM + lg * 8;
        qf[qi][0] = *(const bf16x8*)(qp);
        qf[qi][1] = *(const bf16x8*)(qp + 32);
    }

    const f32x4 fzero = {0.f, 0.f, 0.f, 0.f};
    f32x4 acc[2][4];    // partial O for this kv half
    f32x4 lacc[2];      // partial row sums via ones-MFMA
    #pragma unroll
    for (int qi = 0; qi < 2; ++qi) {
        lacc[qi] = fzero;
        #pragma unroll
        for (int di = 0; di < 4; ++di) acc[qi][di] = fzero;
    }

    bf16x8 ones;
    #pragma unroll
    for (int e = 0; e < 8; ++e) ones[e] = (short)0x3F80;  // bf16 1.0

    const int t0  = wv * 64 + lane;
    const int cbs = ((t0 & 7) ^ ((t0 >> 3) & 7)) << 4;
    const int ghb = wg * 262144;   // kv-half byte offset (2048 kv * 128B)
    const char* kgp = (const char*)(kb + base) + ghb + (((t0 >> 3) << 7) + cbs);
    const char* vgp = (const char*)(vtb + ((size_t)bh << 18)) + ghb + (((t0 >> 3) << 7) + cbs);
    char* const gb = smem + wg * 32768;
    const short* Kb0 = (const short*)(gb);
    const short* Kb1 = (const short*)(gb + 4096);
    const short* Kb2 = (const short*)(gb + 8192);
    const short* Kb3 = (const short*)(gb + 12288);
    const short* Vb0 = (const short*)(gb + 16384);
    const short* Vb1 = (const short*)(gb + 20480);
    const short* Vb2 = (const short*)(gb + 24576);
    const short* Vb3 = (const short*)(gb + 28672);
    char* Ks0 = gb +     0 + wv * 1024;
    char* Ks1 = gb +  4096 + wv * 1024;
    char* Ks2 = gb +  8192 + wv * 1024;
    char* Ks3 = gb + 12288 + wv * 1024;
    char* Vs0 = gb + 16384 + wv * 1024;
    char* Vs1 = gb + 20480 + wv * 1024;
    char* Vs2 = gb + 24576 + wv * 1024;
    char* Vs3 = gb + 28672 + wv * 1024;

    #define MFMA16(a_, b_, c_) __builtin_amdgcn_mfma_f32_16x16x32_bf16(a_, b_, c_, 0, 0, 0)

    #define STAGE2(T_, KS, VS) do {                    \
        gl16(kgp + (T_) * 4096, (KS));                 \
        gl16(vgp + (T_) * 4096, (VS));                 \
    } while (0)

    #define COMPUTE(KR, VR) do {                                               \
        f32x4 s00 = fzero, s01 = fzero, s10 = fzero, s11 = fzero;              \
        __builtin_amdgcn_s_setprio(1);                                         \
        {                                                                      \
            bf16x8 kf_;                                                        \
            kf_ = *(const bf16x8*)(&(KR)[swz(l15, lg * 8)]);                   \
            s00 = MFMA16(kf_, qf[0][0], s00);                                  \
            s10 = MFMA16(kf_, qf[1][0], s10);                                  \
            kf_ = *(const bf16x8*)(&(KR)[swz(l15, 32 + lg * 8)]);              \
            s00 = MFMA16(kf_, qf[0][1], s00);                                  \
            s10 = MFMA16(kf_, qf[1][1], s10);                                  \
            kf_ = *(const bf16x8*)(&(KR)[swz(16 + l15, lg * 8)]);              \
            s01 = MFMA16(kf_, qf[0][0], s01);                                  \
            s11 = MFMA16(kf_, qf[1][0], s11);                                  \
            kf_ = *(const bf16x8*)(&(KR)[swz(16 + l15, 32 + lg * 8)]);         \
            s01 = MFMA16(kf_, qf[0][1], s01);                                  \
            s11 = MFMA16(kf_, qf[1][1], s11);                                  \
        }                                                                      \
        __builtin_amdgcn_s_setprio(0);                                         \
        bf16x8 pa0, pa1;                                                       \
        _Pragma("unroll")                                                      \
        for (int r_ = 0; r_ < 4; ++r_) {                                       \
            pa0[r_]     = f2bf(__builtin_amdgcn_exp2f(s00[r_]));               \
            pa0[4 + r_] = f2bf(__builtin_amdgcn_exp2f(s01[r_]));               \
            pa1[r_]     = f2bf(__builtin_amdgcn_exp2f(s10[r_]));               \
            pa1[4 + r_] = f2bf(__builtin_amdgcn_exp2f(s11[r_]));               \
        }                                                                      \
        __builtin_amdgcn_s_setprio(1);                                         \
        lacc[0] = MFMA16(pa0, ones, lacc[0]);                                  \
        lacc[1] = MFMA16(pa1, ones, lacc[1]);                                  \
        _Pragma("unroll")                                                      \
        for (int di_ = 0; di_ < 4; ++di_) {                                    \
            bf16x8 vf_ = *(const bf16x8*)(&(VR)[swz(di_ * 8 + (l15 >> 1),      \
                                                    (l15 & 1) * 32 + lg * 8)]);\
            acc[0][di_] = MFMA16(pa0, vf_, acc[0][di_]);                       \
            acc[1][di_] = MFMA16(pa1, vf_, acc[1][di_]);                       \
        }                                                                      \
        __builtin_amdgcn_s_setprio(0);                                         \
    } while (0)

    #define AWAITBAR(N_) do {                                      \
        asm volatile("s_waitcnt vmcnt(" #N_ ")" ::: "memory");     \
        __builtin_amdgcn_s_barrier();                              \
        asm volatile("" ::: "memory");                             \
    } while (0)

    // prologue: stage tiles 0,1,2 (6 loads in flight)
    STAGE2(0, Ks0, Vs0);
    STAGE2(1, Ks1, Vs1);
    STAGE2(2, Ks2, Vs2);

    // steady: tiles 0..60 stage t+3; tail 61/62/63 with decreasing waits
    for (int it = 0; it < 15; ++it) {
        const int t = it << 2;
        AWAITBAR(4); STAGE2(t + 3, Ks3, Vs3); COMPUTE(Kb0, Vb0);
        AWAITBAR(4); STAGE2(t + 4, Ks0, Vs0); COMPUTE(Kb1, Vb1);
        AWAITBAR(4); STAGE2(t + 5, Ks1, Vs1); COMPUTE(Kb2, Vb2);
        AWAITBAR(4); STAGE2(t + 6, Ks2, Vs2); COMPUTE(Kb3, Vb3);
    }
    AWAITBAR(4); STAGE2(63, Ks3, Vs3); COMPUTE(Kb0, Vb0);   // t=60
    AWAITBAR(4); COMPUTE(Kb1, Vb1);                          // t=61
    AWAITBAR(2); COMPUTE(Kb2, Vb2);                          // t=62
    AWAITBAR(0); COMPUTE(Kb3, Vb3);                          // t=63
    #undef AWAITBAR
    #undef COMPUTE
    #undef STAGE2
    #undef MFMA16

    // ---- combine the two kv-halves: O = (O0+O1)/(l0+l1) ----
    __syncthreads();   // all K/V reads done; smem reusable as f32 exchange buffer
    float* xch = (float*)smem;
    const int xi = (wv * 64 + lane) * 44;   // 44 f32 stride: 16B-aligned, bank-spread
    if (wg == 1) {
        #pragma unroll
        for (int qi = 0; qi < 2; ++qi) {
            #pragma unroll
            for (int di = 0; di < 4; ++di)
                *(f32x4*)(xch + xi + qi * 16 + di * 4) = acc[qi][di];
            *(f32x4*)(xch + xi + 32 + qi * 4) = lacc[qi];
        }
    }
    __syncthreads();
    if (wg == 0) {
        #pragma unroll
        for (int qi = 0; qi < 2; ++qi) {
            #pragma unroll
            for (int di = 0; di < 4; ++di)
                acc[qi][di] += *(const f32x4*)(xch + xi + qi * 16 + di * 4);
            lacc[qi] += *(const f32x4*)(xch + xi + 32 + qi * 4);
        }
        #pragma unroll
        for (int qi = 0; qi < 2; ++qi) {
            float inv[4];
            #pragma unroll
            for (int r = 0; r < 4; ++r) inv[r] = 1.0f / lacc[qi][r];
            #pragma unroll
            for (int di = 0; di < 4; ++di) {
                const int e = di * 16 + l15;
                #pragma unroll
                for (int r = 0; r < 4; ++r) {
                    const int qn = q0 + wv * 32 + qi * 16 + lg * 4 + r;
                    ob[((size_t)(b * SEQ + qn) << 9) + h * 64 + e] = f2bf(acc[qi][di][r] * inv[r]);
                }
            }
        }
    }
}

// ---------------- proj GEMM (bf16 via gload_lds) + bias + residual: y = x + ao@w^T + bp
__global__ __launch_bounds__(256) void proj_k(
    const short* __restrict__ ao, const short* __restrict__ wpb,
    const float* __restrict__ bp, const float* __restrict__ x,
    float* __restrict__ y)
{
    __shared__ alignas(16) short As[2][128 * 64];
    __shared__ alignas(16) short Bs[2][128 * 64];
    const int tid  = threadIdx.x;
    const int lane = tid & 63;
    const int l15  = lane & 15;
    const int lg   = lane >> 4;
    const int wv   = tid >> 6;
    const int wy   = wv >> 1, wx = wv & 1;
    const int m0 = blockIdx.x * 128;
    const int n0 = blockIdx.y * 128;

    const f32x4 fzero = {0.f, 0.f, 0.f, 0.f};
    f32x4 acc[4][4];
    #pragma unroll
    for (int i = 0; i < 4; ++i)
        #pragma unroll
        for (int j = 0; j < 4; ++j)
            acc[i][j] = fzero;

    const int row0 = wv * 8 + (lane >> 3);
    const int cb   = ((lane & 7) ^ (lane >> 3)) << 4;
    const char* agp = (const char*)ao  + (size_t)(m0 + row0) * 1024 + cb;
    const char* bgp = (const char*)wpb + (size_t)(n0 + row0) * 1024 + cb;
    char* al0 = (char*)&As[0][0] + wv * 1024;
    char* al1 = (char*)&As[1][0] + wv * 1024;
    char* bl0 = (char*)&Bs[0][0] + wv * 1024;
    char* bl1 = (char*)&Bs[1][0] + wv * 1024;

    #define PSTAGE(al, bl, kofs) do {                                  \
        _Pragma("unroll")                                              \
        for (int i_ = 0; i_ < 4; ++i_) {                               \
            gl16(agp + (kofs) + i_ * 32768, (al) + i_ * 4096);         \
            gl16(bgp + (kofs) + i_ * 32768, (bl) + i_ * 4096);         \
        } } while (0)

    PSTAGE(al0, bl0, 0);

    int cur = 0;
    for (int k0 = 0; k0 < CDIM; k0 += 64) {
        asm volatile("s_waitcnt vmcnt(0)" ::: "memory");
        __syncthreads();
        if (k0 + 64 < CDIM) {
            if (cur == 0) PSTAGE(al1, bl1, (k0 + 64) * 2);
            else          PSTAGE(al0, bl0, (k0 + 64) * 2);
        }
        const short* Ac = cur ? &As[1][0] : &As[0][0];
        const short* Bc = cur ? &Bs[1][0] : &Bs[0][0];

        #pragma unroll
        for (int ks = 0; ks < 2; ++ks) {
            bf16x8 afr[4], bfr[4];
            #pragma unroll
            for (int i = 0; i < 4; ++i) {
                afr[i] = *(const bf16x8*)(&Ac[swz(wy * 64 + i * 16 + l15, ks * 32 + lg * 8)]);
                bfr[i] = *(const bf16x8*)(&Bc[swz(wx * 64 + i * 16 + l15, ks * 32 + lg * 8)]);
            }
            #pragma unroll
            for (int i = 0; i < 4; ++i)
                #pragma unroll
                for (int j = 0; j < 4; ++j)
                    acc[i][j] = __builtin_amdgcn_mfma_f32_16x16x32_bf16(afr[i], bfr[j], acc[i][j], 0, 0, 0);
        }
        cur ^= 1;
    }
    #undef PSTAGE

    #pragma unroll
    for (int i = 0; i < 4; ++i) {
        #pragma unroll
        for (int j = 0; j < 4; ++j) {
            const int d = n0 + wx * 64 + j * 16 + l15;
            #pragma unroll
            for (int r = 0; r < 4; ++r) {
                const int m = m0 + wy * 64 + i * 16 + lg * 4 + r;
                const size_t idx = (size_t)m * CDIM + d;
                y[idx] = acc[i][j][r] + bp[d] + x[idx];
            }
        }
    }
}

// ---------------- LayerNorm in place over d_out rows (512 f32 each), 1 wave/row
__global__ __launch_bounds__(256) void ln_k(
    float* __restrict__ y, const float* __restrict__ gm, const float* __restrict__ bt)
{
    const int lane = threadIdx.x & 63;
    const int row  = blockIdx.x * 4 + (threadIdx.x >> 6);
    float* p = y + (size_t)row * CDIM;
    float4 a = *(const float4*)(p + lane * 4);
    float4 b = *(const float4*)(p + 256 + lane * 4);
    float s = a.x + a.y + a.z + a.w + b.x + b.y + b.z + b.w;
    float q = a.x * a.x + a.y * a.y + a.z * a.z + a.w * a.w
            + b.x * b.x + b.y * b.y + b.z * b.z + b.w * b.w;
    #pragma unroll
    for (int mm = 1; mm < 64; mm <<= 1) {
        s += __shfl_xor(s, mm, 64);
        q += __shfl_xor(q, mm, 64);
    }
    const float mean = s * (1.0f / CDIM);
    const float var  = q * (1.0f / CDIM) - mean * mean;
    const float inv  = rsqrtf(var + 1e-5f);
    float4 g0 = *(const float4*)(gm + lane * 4);
    float4 g1 = *(const float4*)(gm + 256 + lane * 4);
    float4 t0 = *(const float4*)(bt + lane * 4);
    float4 t1 = *(const float4*)(bt + 256 + lane * 4);
    float4 r0, r1;
    r0.x = (a.x - mean) * inv * g0.x + t0.x;
    r0.y = (a.y - mean) * inv * g0.y + t0.y;
    r0.z = (a.z - mean) * inv * g0.z + t0.z;
    r0.w = (a.w - mean) * inv * g0.w + t0.w;
    r1.x = (b.x - mean) * inv * g1.x + t1.x;
    r1.y = (b.y - mean) * inv * g1.y + t1.y;
    r1.z = (b.z - mean) * inv * g1.z + t1.z;
    r1.w = (b.w - mean) * inv * g1.w + t1.w;
    *(float4*)(p + lane * 4) = r0;
    *(float4*)(p + 256 + lane * 4) = r1;
}

extern "C" void kernel_launch(void* const* d_in, const int* in_sizes, int n_in,
                              void* d_out, int out_size, void* d_ws, size_t ws_size,
                              hipStream_t stream)
{
    const float* x      = (const float*)d_in[0];
    const float* w_qkv  = (const float*)d_in[1];
    const float* w_proj = (const float*)d_in[2];
    const float* b_proj = (const float*)d_in[3];
    const float* gamma  = (const float*)d_in[4];
    const float* beta   = (const float*)d_in[5];
    float* out = (float*)d_out;

    const size_t qkv_elems = (size_t)16 * SEQ * HDIM;
    short* qb    = (short*)d_ws;
    short* kb    = qb + qkv_elems;
    short* vtb   = kb + qkv_elems;
    short* ob    = vtb + qkv_elems;
    short* xb    = ob;                     // alias: xb dead before attn writes ob
    short* wqkvb = ob + qkv_elems;
    short* wpb   = wqkvb + (size_t)3 * CDIM * CDIM;

    cvt3_k    <<<dim3(1024),   256, 0, stream>>>(
        x, xb, (2 * SEQ * CDIM) / 4,
        w_qkv, wqkvb, (3 * CDIM * CDIM) / 4,
        w_proj, wpb, (CDIM * CDIM) / 4);
    qkv_gemm_k<<<dim3(64, 12), 256, 0, stream>>>(xb, wqkvb, qb, kb, vtb);
    attn_k    <<<dim3(512),    512, 0, stream>>>(qb, kb, vtb, ob);
    proj_k    <<<dim3(64, 4),  256, 0, stream>>>(ob, wpb, b_proj, x, out);
    ln_k      <<<dim3(2048),   256, 0, stream>>>(out, gamma, beta);
}